// Round 14
// baseline (230.727 us; speedup 1.0000x reference)
//
#include <hip/hip_runtime.h>

#define N_SAMP   1024
#define IN_F     512
#define OUT_F    512
#define N_HEADS  32
#define N_SPLITS 4
#define N_GROUPS (N_HEADS * N_SPLITS)
#define DELTA_SCALE 0.1f

// R18: the last unexplored supply-matrix cell -- 1KB-contiguous wave
// segments (R10's geometry, best-ever 0.34 TB/s per wave) at 16 waves/CU
// (R10 only ever ran 8, grid-limited).
//
//   lms_part1k: block = (combo g, col-half ch, k-quarter kb) = 1024 blocks
//     of 256 thr = 4/CU x 4 waves = 16 waves/CU.
//     thread = (c4 = tid&63: cols c0+4*c4 over a 256-col half -> each f4
//     load covers 64 lanes x 16B = 1KB CONTIGUOUS; kq = tid>>6: 32 rows).
//     ch x kb partition W/D bytes -- no duplication. Per 4-row step:
//     4 W + 4 D(nt) f4 loads dist-1, rc combine, J x 4 broadcast FMA.
//     Epilogue: in-block kq-reduction through 24KB LDS Red (2 write +
//     2 accumulate phases) -> 4 ws planes only (8 MB, proven available).
//   lms_reduce4: out = bias[head] + sum_kb ws[kb]  (10 MB traffic, ~2 us).
//
// Spill-proofing (R13/R14/R16 all confounded by scratch): VGPR law
// cap = 256/arg2, real pressure = naive + ~25. J=12: acc 48 + trans 32 +
// rc 16 + addr 14 = 110 <= 128 cap with headroom. E[chunks@J=12] = 1.06.
// nt-D loads + nt ws stores retained (R12 +10%).
// Falls back to verified R17 kernel if ws_size < 8 MB.

typedef float f32x4 __attribute__((ext_vector_type(4)));

__device__ __forceinline__ f32x4 nt_load4(const float* p) {
    return __builtin_nontemporal_load((const f32x4*)p);
}
__device__ __forceinline__ void nt_store4(float* p, f32x4 v) {
    __builtin_nontemporal_store(v, (f32x4*)p);
}

__global__ __launch_bounds__(256, 2) void lms_part1k(
    const float* __restrict__ X, const int* __restrict__ head_ix,
    const int* __restrict__ split_ix, const float* __restrict__ W,
    const float* __restrict__ D, float* __restrict__ ws)
{
    constexpr int J    = 12;           // samples per chunk
    constexpr int KRB  = 128;          // k rows per block (quarter)
    constexpr int KRT  = 32;           // k rows per thread (kq quarter of block)
    constexpr int NST  = KRT / 4;      // 8 steps of 4 rows

    // buf: Xs[J][128] (6 KB) then Red[2][J][64] f4 (24 KB) -- aliased
    __shared__ float buf[2 * J * 64 * 4];   // 24 KB
    __shared__ int   list[N_SAMP];          // 4 KB
    __shared__ int   wsum[4];

    const int g    = blockIdx.y;            // combo = h*N_SPLITS + s
    const int h    = g >> 2;                // N_SPLITS == 4
    const int ch   = blockIdx.x & 1;        // col half
    const int kb   = blockIdx.x >> 1;       // k quarter (0..3)
    const int c0   = ch * 256;
    const int tid  = threadIdx.x;
    const int c4   = tid & 63;              // col-quad: cols c0+4*c4 .. +3
    const int kq   = tid >> 6;              // k sub-quarter (0..3) == wave
    const int lane = tid & 63;
    const int wave = tid >> 6;

    float (*Xs)[KRB] = (float(*)[KRB])buf;
    f32x4* Red = (f32x4*)buf;               // [2][J][64]

    // deterministic order-preserving compaction of samples matching combo g
    int run = 0;
    for (int r = 0; r < N_SAMP / 256; ++r) {
        const int i   = r * 256 + tid;
        const int key = head_ix[i] * N_SPLITS + split_ix[i];
        const bool hit = (key == g);
        const unsigned long long m = __ballot(hit);
        if (lane == 0) wsum[wave] = __popcll(m);
        __syncthreads();
        int base = run;
        for (int w = 0; w < 4; ++w)
            if (w < wave) base += wsum[w];
        if (hit)
            list[base + __popcll(m & ((1ULL << lane) - 1ULL))] = i;
        run += wsum[0] + wsum[1] + wsum[2] + wsum[3];
        __syncthreads();               // wsum consumed before next round
    }
    const int total = run;
    if (total == 0) return;            // block-uniform

    // thread's stripes: rows kb*128+kq*32 .. +31, cols c0+4*c4 .. +3
    const int k0 = kb * KRB + kq * KRT;
    const size_t roff = (size_t)k0 * OUT_F + c0 + 4 * c4;
    const float* wp = W + (size_t)h * (IN_F * OUT_F) + roff;
    const float* dp = D + (size_t)g * (IN_F * OUT_F) + roff;

    for (int s0 = 0; s0 < total; s0 += J) {
        const int nc = min(total - s0, J);

        __syncthreads();               // buf may still hold previous Red
        // stage Xs[s][0..127] = X[list[s0+s]][kb*128 .. +128): 384 float4
        for (int f = 0; f < 2; ++f) {
            const int i = f * 256 + tid;
            if (i < J * (KRB / 4)) {   // 384
                const int s = i >> 5, q = i & 31;
                float4 v = make_float4(0.f, 0.f, 0.f, 0.f);
                if (s < nc)
                    v = *(const float4*)(X + (size_t)list[s0 + s] * IN_F
                                         + kb * KRB + q * 4);
                *(float4*)(&Xs[s][q * 4]) = v;
            }
        }
        __syncthreads();

        f32x4 acc[J];
#pragma unroll
        for (int j = 0; j < J; ++j) acc[j] = (f32x4)0.f;

        // dist-1 pipeline on combined rc (R17 shape): issue loads(t+1) ->
        // FMA(t) -> rc[nxt] combine (vmcnt wait lands after the FMA block)
        f32x4 rc[2][4];
        {
            f32x4 w0[4], d0[4];
#pragma unroll
            for (int u = 0; u < 4; ++u) {
                w0[u] = *(const f32x4*)(wp + (size_t)u * OUT_F);
                d0[u] = nt_load4(dp + (size_t)u * OUT_F);
            }
#pragma unroll
            for (int u = 0; u < 4; ++u)
                rc[0][u] = w0[u] + DELTA_SCALE * d0[u];
        }

#pragma unroll 2
        for (int st = 0; st < NST; ++st) {
            const int cb = st & 1, nb = cb ^ 1;
            // issue loads for t+1 (clamped tail: redundant L1-hit re-load
            // keeps the body branch-free)
            const int nr = (st + 1 < NST) ? (st + 1) * 4 : st * 4;
            f32x4 wl[4], dl[4];
#pragma unroll
            for (int u = 0; u < 4; ++u) {
                wl[u] = *(const f32x4*)(wp + (size_t)(nr + u) * OUT_F);
                dl[u] = nt_load4(dp + (size_t)(nr + u) * OUT_F);
            }

            // FMA(t) against rc[cb] -- no dependence on wl/dl
            const float* xb = &Xs[0][kq * KRT + st * 4];
#pragma unroll
            for (int j = 0; j < J; ++j) {
                const float4 xv = *(const float4*)(xb + j * KRB); // broadcast
                acc[j] += xv.x * rc[cb][0];
                acc[j] += xv.y * rc[cb][1];
                acc[j] += xv.z * rc[cb][2];
                acc[j] += xv.w * rc[cb][3];
            }

            // combine for t+1 (first use of wl/dl -> wait sits here)
#pragma unroll
            for (int u = 0; u < 4; ++u)
                rc[nb][u] = wl[u] + DELTA_SCALE * dl[u];
        }

        // ---- in-block kq-reduction: 2 write + 2 accumulate phases ----
        __syncthreads();               // Xs fully consumed; reuse buf as Red
        if (kq < 2) {
#pragma unroll
            for (int j = 0; j < J; ++j)
                Red[(kq * J + j) * 64 + c4] = acc[j];
        }
        __syncthreads();
        if (kq >= 2) {
            const int p = kq - 2;
#pragma unroll
            for (int j = 0; j < J; ++j) {
                f32x4 r = Red[(p * J + j) * 64 + c4];
                Red[(p * J + j) * 64 + c4] = r + acc[j];
            }
        }
        __syncthreads();

        // sole-owner: sum the 2 halves, nt store to ws plane kb
        // J*64 = 768 f4 slots over 256 threads = 3 each
#pragma unroll
        for (int t = 0; t < 3; ++t) {
            const int oi = t * 256 + tid;
            const int j  = oi >> 6, cc = oi & 63;
            if (j < nc) {
                const f32x4 s = Red[(0 * J + j) * 64 + cc]
                              + Red[(1 * J + j) * 64 + cc];
                float* op = ws + ((size_t)kb * N_SAMP + list[s0 + j]) * OUT_F
                          + c0 + cc * 4;
                nt_store4(op, s);
            }
        }
    }
}

// out[i][c] = bias[head_ix[i]][c] + sum_kb ws[kb][i][c]
__global__ __launch_bounds__(256, 4) void lms_reduce4(
    const float* __restrict__ ws, const int* __restrict__ head_ix,
    const float* __restrict__ bias, float* __restrict__ out)
{
    const int gid = blockIdx.x * 256 + threadIdx.x;
    const int i   = gid >> 7;          // sample
    const int c4  = gid & 127;         // f4 index within 512 cols
    const int h   = head_ix[i];

    f32x4 s = *(const f32x4*)(bias + (size_t)h * OUT_F + 4 * c4);
#pragma unroll
    for (int p = 0; p < 4; ++p)
        s += nt_load4(ws + ((size_t)p * N_SAMP + i) * OUT_F + 4 * c4);
    *(f32x4*)(out + (size_t)i * OUT_F + 4 * c4) = s;
}

// ---------------------------------------------------------------------------
// Fallback: verified R17 kernel (bench 229.7 us), used only if ws < 8 MB.
__global__ __launch_bounds__(256, 2) void lms_fused_nt_w4(
    const float* __restrict__ X, const int* __restrict__ head_ix,
    const int* __restrict__ split_ix, const float* __restrict__ W,
    const float* __restrict__ D, const float* __restrict__ bias,
    float* __restrict__ out)
{
    constexpr int J    = 12;
    constexpr int KQ   = 16;
    constexpr int KT   = IN_F / KQ;
    constexpr int NST  = KT / 4;

    __shared__ float buf[J * IN_F];
    __shared__ int   list[N_SAMP];
    __shared__ int   wsum[4];

    const int g    = blockIdx.y;
    const int h    = g >> 2;
    const int c0   = blockIdx.x * 64;
    const int tid  = threadIdx.x;
    const int c4   = tid & 15;
    const int kq   = tid >> 4;
    const int lane = tid & 63;
    const int wave = tid >> 6;

    int run = 0;
    for (int r = 0; r < N_SAMP / 256; ++r) {
        const int i   = r * 256 + tid;
        const int key = head_ix[i] * N_SPLITS + split_ix[i];
        const bool hit = (key == g);
        const unsigned long long m = __ballot(hit);
        if (lane == 0) wsum[wave] = __popcll(m);
        __syncthreads();
        int base = run;
        for (int w = 0; w < 4; ++w)
            if (w < wave) base += wsum[w];
        if (hit)
            list[base + __popcll(m & ((1ULL << lane) - 1ULL))] = i;
        run += wsum[0] + wsum[1] + wsum[2] + wsum[3];
        __syncthreads();
    }
    const int total = run;
    if (total == 0) return;

    const size_t roff = (size_t)(kq * KT) * OUT_F + c0 + c4 * 4;
    const float* wp = W + (size_t)h * (IN_F * OUT_F) + roff;
    const float* dp = D + (size_t)g * (IN_F * OUT_F) + roff;

    for (int s0 = 0; s0 < total; s0 += J) {
        const int nc = min(total - s0, J);

        __syncthreads();
#pragma unroll
        for (int f = 0; f < 6; ++f) {
            const int i = f * 256 + tid;
            const int s = i >> 7, q = i & 127;
            float4 v = make_float4(0.f, 0.f, 0.f, 0.f);
            if (s < nc)
                v = *(const float4*)(X + (size_t)list[s0 + s] * IN_F + q * 4);
            *(float4*)(&buf[s * IN_F + q * 4]) = v;
        }
        __syncthreads();

        f32x4 acc[J];
#pragma unroll
        for (int j = 0; j < J; ++j) acc[j] = (f32x4)0.f;

        f32x4 rc[2][4];
        {
            f32x4 w0[4], d0[4];
#pragma unroll
            for (int u = 0; u < 4; ++u) {
                w0[u] = *(const f32x4*)(wp + (size_t)u * OUT_F);
                d0[u] = nt_load4(dp + (size_t)u * OUT_F);
            }
#pragma unroll
            for (int u = 0; u < 4; ++u)
                rc[0][u] = w0[u] + DELTA_SCALE * d0[u];
        }

#pragma unroll
        for (int st = 0; st < NST; ++st) {
            const int cb = st & 1, nb = cb ^ 1;
            const int nr = (st + 1 < NST) ? (st + 1) * 4 : st * 4;
            f32x4 wl[4], dl[4];
#pragma unroll
            for (int u = 0; u < 4; ++u) {
                wl[u] = *(const f32x4*)(wp + (size_t)(nr + u) * OUT_F);
                dl[u] = nt_load4(dp + (size_t)(nr + u) * OUT_F);
            }

            const float* xb = &buf[kq * KT + st * 4];
#pragma unroll
            for (int j = 0; j < J; ++j) {
                const float4 xv = *(const float4*)(xb + j * IN_F);
                acc[j] += xv.x * rc[cb][0];
                acc[j] += xv.y * rc[cb][1];
                acc[j] += xv.z * rc[cb][2];
                acc[j] += xv.w * rc[cb][3];
            }

#pragma unroll
            for (int u = 0; u < 4; ++u)
                rc[nb][u] = wl[u] + DELTA_SCALE * dl[u];
        }

        __syncthreads();
        f32x4* Red = (f32x4*)buf;
        if (kq < 8) {
#pragma unroll
            for (int j = 0; j < J; ++j)
                Red[(kq * J + j) * 16 + c4] = acc[j];
        }
        __syncthreads();
        if (kq >= 8) {
            const int q = kq - 8;
#pragma unroll
            for (int j = 0; j < J; ++j) {
                f32x4 r = Red[(q * J + j) * 16 + c4];
                Red[(q * J + j) * 16 + c4] = r + acc[j];
            }
        }
        __syncthreads();

        if (tid < J * 16) {
            const int j  = tid >> 4;
            const int cc = tid & 15;
            if (j < nc) {
                f32x4 s = (f32x4)0.f;
#pragma unroll
                for (int q = 0; q < 8; ++q)
                    s += Red[(q * J + j) * 16 + cc];
                const f32x4 bv = *(const f32x4*)(bias + (size_t)h * OUT_F
                                                 + c0 + cc * 4);
                float* op = out + (size_t)list[s0 + j] * OUT_F + c0 + cc * 4;
                nt_store4(op, s + bv);
            }
        }
    }
}

extern "C" void kernel_launch(void* const* d_in, const int* in_sizes, int n_in,
                              void* d_out, int out_size, void* d_ws, size_t ws_size,
                              hipStream_t stream) {
    const float* X        = (const float*)d_in[0];
    const int*   head_ix  = (const int*)d_in[1];
    const int*   split_ix = (const int*)d_in[2];
    const float* W        = (const float*)d_in[3];
    const float* D        = (const float*)d_in[4];
    const float* bias     = (const float*)d_in[5];
    float*       out      = (float*)d_out;

    const size_t ws_need = (size_t)4 * N_SAMP * OUT_F * sizeof(float); // 8 MB
    if (ws_size >= ws_need) {
        float* ws = (float*)d_ws;
        // 1024 blocks (128 combos x 2 col-halves x 4 k-quarters) = 4/CU x
        // 4 waves = 16 waves/CU; every W/D load = 1KB contiguous per wave.
        lms_part1k<<<dim3(8, N_GROUPS), 256, 0, stream>>>(
            X, head_ix, split_ix, W, D, ws);
        // 512 blocks: 8 MB + bias read, 2 MB write.
        lms_reduce4<<<dim3((N_SAMP * OUT_F / 4) / 256), 256, 0, stream>>>(
            ws, head_ix, bias, out);
    } else {
        // verified R17 fallback (bench 229.7)
        dim3 gf(OUT_F / 64, N_GROUPS);
        lms_fused_nt_w4<<<gf, 256, 0, stream>>>(
            X, head_ix, split_ix, W, D, bias, out);
    }
}